// Round 7
// baseline (69.651 us; speedup 1.0000x reference)
//
#include <hip/hip_runtime.h>

namespace {
constexpr int H = 512;
constexpr int W = 512;
constexpr int NC = 96;                 // 32 images * 3 channels (independent planes)
constexpr int RSTRIP = 32;             // output rows per wave
constexpr int SPP = H / RSTRIP;        // 16 row-strips per plane
constexpr int NQ = 4;                  // four 128-col quarters per row
constexpr int NSTRIPS = NC * NQ * SPP; // 6144 waves = 24/CU supplied
constexpr int WPB = 4;                 // waves per block
constexpr int NTHR = WPB * 64;         // 256
constexpr int NBLK = NSTRIPS / WPB;    // 1536 blocks = 6 blocks/CU
constexpr float INV_K2 = 1.0f / 49.0f;
constexpr float INV_TOTAL = 1.0f / (32.0f * 3.0f * 512.0f * 512.0f);
}

// One row step, 2 columns per lane. P8/P4 compile-time ring phases -> static indices.
template <int P8, int P4, bool EMIT>
__device__ __forceinline__ void proc_row(
    const float2* __restrict__ pred2, const float2* __restrict__ targ2,
    const float4* __restrict__ pred4, const float4* __restrict__ targ4,
    int y, int base2, int base4, int col2, int q32, int lane,
    bool haloL, bool haloR,
    float (&hr)[8][2], float (&dr)[4][2], float (&vs)[2], float& acc)
{
    float2 d = make_float2(0.f, 0.f);
    float4 g = make_float4(0.f, 0.f, 0.f, 0.f);   // cross-quarter halo (lanes 0,1,62,63)
    if ((unsigned)y < (unsigned)H) {
        const int i2 = base2 + y * (W / 2) + col2;
        const float2 a = pred2[i2];
        const float2 b = targ2[i2];
        d.x = a.x - b.x;
        d.y = a.y - b.y;
        if (haloL | haloR) {
            const int i4 = base4 + y * (W / 4) + q32 + (haloL ? -1 : 32);
            const float4 ga = pred4[i4];
            const float4 gb = targ4[i4];
            g.x = ga.x - gb.x; g.y = ga.y - gb.y;
            g.z = ga.z - gb.z; g.w = ga.w - gb.w;
        }
    }

    // halo: window is [c-3, c+3] for own cols c0=2*lane, c0+1
    float u2  = __shfl_up(d.y, 2);     // col c0-3
    float u1x = __shfl_up(d.x, 1);     // col c0-2
    float u1y = __shfl_up(d.y, 1);     // col c0-1
    float n1x = __shfl_down(d.x, 1);   // col c0+2
    float n1y = __shfl_down(d.y, 1);   // col c0+3
    float n2  = __shfl_down(d.x, 2);   // col c0+4
    if (lane == 0)       { u2 = g.y; u1x = g.z; u1y = g.w; }
    else if (lane == 1)  { u2 = g.w; }
    else if (lane == 62) { n2 = g.x; }
    else if (lane == 63) { n1x = g.x; n1y = g.y; n2 = g.z; }

    const float h0 = ((u2 + u1x) + (u1y + d.x)) + ((d.y + n1x) + n1y);
    const float h1 = h0 - u2 + n2;

    constexpr int S  = P8 & 7;
    constexpr int So = (P8 + 1) & 7;   // h from 7 rows ago
    constexpr int Q  = P4 & 3;
    constexpr int Qo = (P4 + 1) & 3;   // d from 3 rows ago

    vs[0] += h0 - hr[So][0]; hr[S][0] = h0;
    vs[1] += h1 - hr[So][1]; hr[S][1] = h1;

    if (EMIT) {
        acc += fabsf(dr[Qo][0] - vs[0] * INV_K2)
             + fabsf(dr[Qo][1] - vs[1] * INV_K2);
    }

    dr[Q][0] = d.x;
    dr[Q][1] = d.y;
}

// NOTE: min-waves arg deliberately 4 (VGPR cap 128, non-binding). Forcing 6/8
// (R3/R4) makes the allocator spill the ring arrays wholesale -> 300+ MB scratch.
__global__ __launch_bounds__(NTHR, 4) void lcl_partial(
    const float2* __restrict__ pred2, const float2* __restrict__ targ2,
    float* __restrict__ partials)
{
    const float4* pred4 = (const float4*)pred2;
    const float4* targ4 = (const float4*)targ2;

    const int tid   = threadIdx.x;
    const int lane  = tid & 63;
    const int wv    = tid >> 6;
    const int strip = blockIdx.x * WPB + wv;
    const int plane = strip >> 6;                  // 64 strips per plane
    const int rem   = strip & 63;
    const int quarter = rem >> 4;
    const int y0    = (rem & 15) * RSTRIP;
    const int base2 = plane * (H * (W / 2));
    const int base4 = plane * (H * (W / 4));
    const int col2  = quarter * 64 + lane;         // float2 index within row
    const int q32   = quarter * 32;                // float4 index of quarter start
    const bool haloL = (lane <= 1)  && (quarter > 0);
    const bool haloR = (lane >= 62) && (quarter < 3);

    float hr[8][2], dr[4][2], vs[2];
#pragma unroll
    for (int s = 0; s < 8; ++s) { hr[s][0] = 0.f; hr[s][1] = 0.f; }
#pragma unroll
    for (int s = 0; s < 4; ++s) { dr[s][0] = 0.f; dr[s][1] = 0.f; }
    vs[0] = 0.f; vs[1] = 0.f;
    float acc = 0.f;

    // prologue: rows y0-3 .. y0+2 (phases 0..5), no output yet
    proc_row<0, 0, false>(pred2, targ2, pred4, targ4, y0 - 3, base2, base4, col2, q32, lane, haloL, haloR, hr, dr, vs, acc);
    proc_row<1, 1, false>(pred2, targ2, pred4, targ4, y0 - 2, base2, base4, col2, q32, lane, haloL, haloR, hr, dr, vs, acc);
    proc_row<2, 2, false>(pred2, targ2, pred4, targ4, y0 - 1, base2, base4, col2, q32, lane, haloL, haloR, hr, dr, vs, acc);
    proc_row<3, 3, false>(pred2, targ2, pred4, targ4, y0    , base2, base4, col2, q32, lane, haloL, haloR, hr, dr, vs, acc);
    proc_row<4, 0, false>(pred2, targ2, pred4, targ4, y0 + 1, base2, base4, col2, q32, lane, haloL, haloR, hr, dr, vs, acc);
    proc_row<5, 1, false>(pred2, targ2, pred4, targ4, y0 + 2, base2, base4, col2, q32, lane, haloL, haloR, hr, dr, vs, acc);

    // steady state: 4 runtime iterations x 8-row unrolled body (phases repeat mod 8)
#pragma unroll 1
    for (int b = 0; b < 4; ++b) {
        const int yb = y0 + 3 + b * 8;
        proc_row<6, 2, true>(pred2, targ2, pred4, targ4, yb    , base2, base4, col2, q32, lane, haloL, haloR, hr, dr, vs, acc);
        proc_row<7, 3, true>(pred2, targ2, pred4, targ4, yb + 1, base2, base4, col2, q32, lane, haloL, haloR, hr, dr, vs, acc);
        proc_row<0, 0, true>(pred2, targ2, pred4, targ4, yb + 2, base2, base4, col2, q32, lane, haloL, haloR, hr, dr, vs, acc);
        proc_row<1, 1, true>(pred2, targ2, pred4, targ4, yb + 3, base2, base4, col2, q32, lane, haloL, haloR, hr, dr, vs, acc);
        proc_row<2, 2, true>(pred2, targ2, pred4, targ4, yb + 4, base2, base4, col2, q32, lane, haloL, haloR, hr, dr, vs, acc);
        proc_row<3, 3, true>(pred2, targ2, pred4, targ4, yb + 5, base2, base4, col2, q32, lane, haloL, haloR, hr, dr, vs, acc);
        proc_row<4, 0, true>(pred2, targ2, pred4, targ4, yb + 6, base2, base4, col2, q32, lane, haloL, haloR, hr, dr, vs, acc);
        proc_row<5, 1, true>(pred2, targ2, pred4, targ4, yb + 7, base2, base4, col2, q32, lane, haloL, haloR, hr, dr, vs, acc);
    }

    // wave reduce, one partial per strip
#pragma unroll
    for (int off = 32; off > 0; off >>= 1)
        acc += __shfl_down(acc, off, 64);
    if (lane == 0) partials[strip] = acc;
}

__global__ __launch_bounds__(256) void lcl_reduce(const float* __restrict__ partials,
                                                  float* __restrict__ out)
{
    __shared__ float wred[4];
    const int tid = threadIdx.x;
    float s = 0.0f;
    for (int i = tid; i < NSTRIPS; i += 256) s += partials[i];
#pragma unroll
    for (int off = 32; off > 0; off >>= 1)
        s += __shfl_down(s, off, 64);
    if ((tid & 63) == 0) wred[tid >> 6] = s;
    __syncthreads();
    if (tid == 0) out[0] = ((wred[0] + wred[1]) + (wred[2] + wred[3])) * INV_TOTAL;
}

extern "C" void kernel_launch(void* const* d_in, const int* in_sizes, int n_in,
                              void* d_out, int out_size, void* d_ws, size_t ws_size,
                              hipStream_t stream) {
    const float2* pred2 = (const float2*)d_in[0];
    const float2* targ2 = (const float2*)d_in[1];
    float* out      = (float*)d_out;
    float* partials = (float*)d_ws;   // NSTRIPS floats = 24 KB

    lcl_partial<<<NBLK, NTHR, 0, stream>>>(pred2, targ2, partials);
    lcl_reduce<<<1, 256, 0, stream>>>(partials, out);
}

// Round 8
// 47.693 us; speedup vs baseline: 1.4604x; 1.4604x over previous
//
#include <hip/hip_runtime.h>

namespace {
constexpr int H = 512;
constexpr int W = 512;
constexpr int NC = 96;                   // 32 images * 3 channels (independent planes)
constexpr int RSTRIP = 32;               // output rows per block
constexpr int SPP = H / RSTRIP;          // 16 strips per plane
constexpr int NBLK = NC * SPP;           // 1536 blocks
constexpr int NTHR = 512;                // 8 waves; 1 column per thread
constexpr int TROWS = RSTRIP + 6;        // 38 tile rows (±3 halo)
constexpr int LROW = W + 8;              // 520 words per LDS row (zero pads both sides)
constexpr int NF4 = TROWS * (W / 4);     // 4864 float4 slots to stage
constexpr float INV_K2 = 1.0f / 49.0f;
constexpr float INV_TOTAL = 1.0f / (32.0f * 3.0f * 512.0f * 512.0f);
}

// One row step for one column. P8/P4 compile-time ring phases -> static indices.
// lds_row points at word (r*LROW + c + 1): words [c+1 .. c+7] = d[row r][c-3 .. c+3].
template <int P8, int P4, bool EMIT>
__device__ __forceinline__ void step(const float* __restrict__ lds_row,
                                     float (&hr)[8], float (&dr)[4],
                                     float& vs, float& acc)
{
    const float w0 = lds_row[0];
    const float w1 = lds_row[1];
    const float w2 = lds_row[2];
    const float w3 = lds_row[3];   // center: d[r][c]
    const float w4 = lds_row[4];
    const float w5 = lds_row[5];
    const float w6 = lds_row[6];
    const float h = ((w0 + w1) + (w2 + w3)) + ((w4 + w5) + w6);

    constexpr int S  = P8 & 7;
    constexpr int So = (P8 + 1) & 7;   // h from 7 steps ago
    constexpr int Q  = P4 & 3;
    constexpr int Qo = (P4 + 1) & 3;   // d from 3 steps ago

    vs += h - hr[So];
    hr[S] = h;
    if (EMIT) acc += fabsf(dr[Qo] - vs * INV_K2);
    dr[Q] = w3;
}

// NOTE: min-waves=4 gives VGPR cap 128 vs expected natural ~80 (relaxed).
// Forcing near the natural count (R3/R4: caps 85/64 vs need) spills the rings.
__global__ __launch_bounds__(NTHR, 4) void lcl_partial(
    const float4* __restrict__ pred4, const float4* __restrict__ targ4,
    float* __restrict__ partials)
{
    __shared__ float sm[TROWS * LROW + 8];   // 38x520 tile + 8-slot wave-reduce tail

    const int t     = threadIdx.x;
    const int plane = blockIdx.x >> 4;            // / SPP
    const int y0    = (blockIdx.x & 15) * RSTRIP;
    const int base4 = plane * (H * (W / 4));

    // zero the side pads: words {1,2,3} and {516,517,518} of each row
    if (t < TROWS * 6) {
        const int r = t / 6;
        const int k = t - 6 * r;
        sm[r * LROW + (k < 3 ? 1 + k : 513 + k)] = 0.f;
    }

    // stage d = pred - target, float4-granular, 10 independent iterations (MLP)
#pragma unroll
    for (int it = 0; it < 10; ++it) {
        const int i = t + it * NTHR;
        if (it < 9 || i < NF4) {                  // it<9 always in range (4608+511 < ... guarded)
            const int r  = i >> 7;                // / 128 float4s per row
            const int cw = i & 127;
            const int y  = y0 - 3 + r;
            float4 d4 = make_float4(0.f, 0.f, 0.f, 0.f);
            if ((unsigned)y < (unsigned)H) {
                const float4 a = pred4[base4 + y * (W / 4) + cw];
                const float4 b = targ4[base4 + y * (W / 4) + cw];
                d4 = make_float4(a.x - b.x, a.y - b.y, a.z - b.z, a.w - b.w);
            }
            *(float4*)&sm[r * LROW + 4 + 4 * cw] = d4;
        }
    }
    __syncthreads();   // the ONLY tile barrier

    // compute: this thread owns column c = t for all 32 output rows
    float hr[8], dr[4];
#pragma unroll
    for (int s = 0; s < 8; ++s) hr[s] = 0.f;
#pragma unroll
    for (int s = 0; s < 4; ++s) dr[s] = 0.f;
    float vs = 0.f, acc = 0.f;

    const float* p = &sm[t + 1];

    // prologue: tile rows 0..5 (no emit)
    step<0, 0, false>(p + 0 * LROW, hr, dr, vs, acc);
    step<1, 1, false>(p + 1 * LROW, hr, dr, vs, acc);
    step<2, 2, false>(p + 2 * LROW, hr, dr, vs, acc);
    step<3, 3, false>(p + 3 * LROW, hr, dr, vs, acc);
    step<4, 0, false>(p + 4 * LROW, hr, dr, vs, acc);
    step<5, 1, false>(p + 5 * LROW, hr, dr, vs, acc);

    // steady state: rows 6..37, phases repeat mod 8
#pragma unroll 1
    for (int b = 0; b < 4; ++b) {
        const float* q = p + (6 + 8 * b) * LROW;
        step<6, 2, true>(q + 0 * LROW, hr, dr, vs, acc);
        step<7, 3, true>(q + 1 * LROW, hr, dr, vs, acc);
        step<0, 0, true>(q + 2 * LROW, hr, dr, vs, acc);
        step<1, 1, true>(q + 3 * LROW, hr, dr, vs, acc);
        step<2, 2, true>(q + 4 * LROW, hr, dr, vs, acc);
        step<3, 3, true>(q + 5 * LROW, hr, dr, vs, acc);
        step<4, 0, true>(q + 6 * LROW, hr, dr, vs, acc);
        step<5, 1, true>(q + 7 * LROW, hr, dr, vs, acc);
    }

    // block reduce: wave shfl-reduce -> 8 partials in LDS tail -> thread 0
#pragma unroll
    for (int off = 32; off > 0; off >>= 1)
        acc += __shfl_down(acc, off, 64);
    float* wred = &sm[TROWS * LROW];
    if ((t & 63) == 0) wred[t >> 6] = acc;
    __syncthreads();
    if (t == 0) {
        float s = ((wred[0] + wred[1]) + (wred[2] + wred[3]))
                + ((wred[4] + wred[5]) + (wred[6] + wred[7]));
        partials[blockIdx.x] = s;
    }
}

__global__ __launch_bounds__(256) void lcl_reduce(const float* __restrict__ partials,
                                                  float* __restrict__ out)
{
    __shared__ float wred[4];
    const int tid = threadIdx.x;
    float s = 0.0f;
    for (int i = tid; i < NBLK; i += 256) s += partials[i];
#pragma unroll
    for (int off = 32; off > 0; off >>= 1)
        s += __shfl_down(s, off, 64);
    if ((tid & 63) == 0) wred[tid >> 6] = s;
    __syncthreads();
    if (tid == 0) out[0] = ((wred[0] + wred[1]) + (wred[2] + wred[3])) * INV_TOTAL;
}

extern "C" void kernel_launch(void* const* d_in, const int* in_sizes, int n_in,
                              void* d_out, int out_size, void* d_ws, size_t ws_size,
                              hipStream_t stream) {
    const float4* pred4 = (const float4*)d_in[0];
    const float4* targ4 = (const float4*)d_in[1];
    float* out      = (float*)d_out;
    float* partials = (float*)d_ws;   // NBLK floats = 6 KB

    lcl_partial<<<NBLK, NTHR, 0, stream>>>(pred4, targ4, partials);
    lcl_reduce<<<1, 256, 0, stream>>>(partials, out);
}